// Round 8
// baseline (901.032 us; speedup 1.0000x reference)
//
#include <hip/hip_runtime.h>
#include <math.h>

#define DIMC 128
#define FINC 78
#define REPW 1152        // 9 * 128
#define SCAN_TILE 1024   // elements per scan tile (256 threads x 4)

typedef __attribute__((ext_vector_type(8))) short short8x;
typedef __attribute__((ext_vector_type(4))) float f32x4;

__device__ inline float b2f(unsigned short u) {
    union { unsigned int i; float f; } v; v.i = ((unsigned int)u) << 16; return v.f;
}
__device__ inline unsigned short f2b(float f) {
    union { float f; unsigned int i; } v; v.f = f;
    unsigned int r = (v.i + 0x7FFFu + ((v.i >> 16) & 1u)) >> 16;
    return (unsigned short)r;
}
__device__ inline void hl2f8(uint4 h, uint4 l, float* f) {
    unsigned int hw[4] = {h.x, h.y, h.z, h.w}, lw[4] = {l.x, l.y, l.z, l.w};
#pragma unroll
    for (int j = 0; j < 4; ++j) {
        f[2 * j]     = b2f((unsigned short)(hw[j] & 0xFFFF)) + b2f((unsigned short)(lw[j] & 0xFFFF));
        f[2 * j + 1] = b2f((unsigned short)(hw[j] >> 16))    + b2f((unsigned short)(lw[j] >> 16));
    }
}
__device__ inline void f82hl(const float* f, uint4& h, uint4& l) {
    unsigned int hw[4], lw[4];
#pragma unroll
    for (int j = 0; j < 4; ++j) {
        unsigned short h0 = f2b(f[2 * j]), h1 = f2b(f[2 * j + 1]);
        unsigned short l0 = f2b(f[2 * j] - b2f(h0)), l1 = f2b(f[2 * j + 1] - b2f(h1));
        hw[j] = (unsigned int)h0 | ((unsigned int)h1 << 16);
        lw[j] = (unsigned int)l0 | ((unsigned int)l1 << 16);
    }
    h = make_uint4(hw[0], hw[1], hw[2], hw[3]);
    l = make_uint4(lw[0], lw[1], lw[2], lw[3]);
}

// ---------------- setup kernels ----------------

__global__ void k_fill_int(int* __restrict__ p, int v, int n) {
    int i = blockIdx.x * blockDim.x + threadIdx.x;
    if (i < n) p[i] = v;
}

__global__ void k_fill(float* __restrict__ p, float v, int n) {
    int i = blockIdx.x * blockDim.x + threadIdx.x;
    if (i < n) p[i] = v;
}

__global__ void k_count(const int* __restrict__ dst, int* __restrict__ cnt, int E) {
    int e = blockIdx.x * blockDim.x + threadIdx.x;
    if (e < E) atomicAdd(&cnt[dst[e]], 1);
}

__launch_bounds__(256)
__global__ void k_tilesum(const int* __restrict__ cnt, int* __restrict__ tileSum, int N) {
    __shared__ int red[256];
    int base = blockIdx.x * SCAN_TILE;
    int s = 0;
    for (int i = threadIdx.x; i < SCAN_TILE; i += 256) {
        int idx = base + i;
        if (idx < N) s += cnt[idx];
    }
    red[threadIdx.x] = s;
    __syncthreads();
    for (int d = 128; d > 0; d >>= 1) {
        if (threadIdx.x < d) red[threadIdx.x] += red[threadIdx.x + d];
        __syncthreads();
    }
    if (threadIdx.x == 0) tileSum[blockIdx.x] = red[0];
}

__launch_bounds__(256)
__global__ void k_tilescan(const int* __restrict__ tileSum, int* __restrict__ tileOff,
                           int* __restrict__ rowptr, int T, int N) {
    __shared__ int sh[256];
    int t = threadIdx.x;
    int orig = (t < T) ? tileSum[t] : 0;
    sh[t] = orig;
    __syncthreads();
    for (int d = 1; d < 256; d <<= 1) {
        int v = (t >= d) ? sh[t - d] : 0;
        __syncthreads();
        sh[t] += v;
        __syncthreads();
    }
    if (t < T) tileOff[t] = sh[t] - orig;
    if (t == 255) rowptr[N] = sh[255];
}

__launch_bounds__(256)
__global__ void k_tileemit(const int* __restrict__ cnt, const int* __restrict__ tileOff,
                           int* __restrict__ rowptr, int* __restrict__ cursor,
                           float* __restrict__ dis, int N) {
    __shared__ int sh[256];
    int t = threadIdx.x;
    int base = blockIdx.x * SCAN_TILE;
    int idx0 = base + t * 4;
    int v0 = 0, v1 = 0, v2 = 0, v3 = 0;
    if (idx0 + 3 < N) {
        int4 v = *(const int4*)(cnt + idx0);
        v0 = v.x; v1 = v.y; v2 = v.z; v3 = v.w;
    } else {
        if (idx0 + 0 < N) v0 = cnt[idx0 + 0];
        if (idx0 + 1 < N) v1 = cnt[idx0 + 1];
        if (idx0 + 2 < N) v2 = cnt[idx0 + 2];
        if (idx0 + 3 < N) v3 = cnt[idx0 + 3];
    }
    int s0 = v0, s1 = s0 + v1, s2 = s1 + v2, s3 = s2 + v3;
    sh[t] = s3;
    __syncthreads();
    for (int d = 1; d < 256; d <<= 1) {
        int v = (t >= d) ? sh[t - d] : 0;
        __syncthreads();
        sh[t] += v;
        __syncthreads();
    }
    int gbase = tileOff[blockIdx.x] + ((t == 0) ? 0 : sh[t - 1]);
    int ex[4] = {0, s0, s1, s2};
    int vv[4] = {v0, v1, v2, v3};
#pragma unroll
    for (int j = 0; j < 4; ++j) {
        int idx = idx0 + j;
        if (idx < N) {
            int r = gbase + ex[j];
            rowptr[idx] = r;
            cursor[idx] = r;
            dis[idx] = rsqrtf((float)vv[j] + 1.0f);
        }
    }
}

__global__ void k_scatter(const int* __restrict__ src, const int* __restrict__ dst,
                          int* __restrict__ cursor, int* __restrict__ col, int E) {
    int e = blockIdx.x * blockDim.x + threadIdx.x;
    if (e < E) {
        int pos = atomicAdd(&cursor[dst[e]], 1);
        col[pos] = src[e];
    }
}

__global__ void k_bounds(const int* __restrict__ batch, int* __restrict__ start, int N, int G) {
    int g = blockIdx.x * blockDim.x + threadIdx.x;
    if (g <= G) {
        int lo = 0, hi = N;
        while (lo < hi) { int mid = (lo + hi) >> 1; if (batch[mid] < g) lo = mid + 1; else hi = mid; }
        start[g] = lo;
    }
}

// ---------------- conversions ----------------

// x [N x 78] fp32 -> hi/lo planes [N x 96] (zero-padded)
__global__ void k_cvt_x(const float* __restrict__ x, unsigned short* __restrict__ xhi,
                        unsigned short* __restrict__ xlo, int N) {
    int i = blockIdx.x * blockDim.x + threadIdx.x;
    if (i < N * 96) {
        int n = i / 96, k = i - n * 96;
        float v = (k < FINC) ? x[(size_t)n * FINC + k] : 0.f;
        unsigned short hi = f2b(v);
        xhi[i] = hi;
        xlo[i] = f2b(v - b2f(hi));
    }
}

// weights -> transposed bf16 hi/lo [n][k]
__global__ void k_cvt_w(const float* __restrict__ s0, const float* __restrict__ s1,
                        const float* __restrict__ s2, const float* __restrict__ s3,
                        const float* __restrict__ s4, const float* __restrict__ s5,
                        unsigned short* __restrict__ whi, unsigned short* __restrict__ wlo) {
    int my = blockIdx.y;
    const float* src; int Ksrc, KP; size_t dstoff;
    const size_t o96 = (size_t)128 * 96, o128 = (size_t)128 * 128;
    switch (my) {
        case 0: src = s0; Ksrc = 78;  KP = 96;  dstoff = 0; break;             // gcn1
        case 1: src = s1; Ksrc = 78;  KP = 96;  dstoff = o96; break;           // gin0_w1
        case 2: src = s2; Ksrc = 128; KP = 128; dstoff = 2 * o96; break;       // gcn2
        case 3: src = s3; Ksrc = 128; KP = 128; dstoff = 2 * o96 + o128; break;        // gin0_w2
        case 4: src = s4; Ksrc = 128; KP = 128; dstoff = 2 * o96 + 2 * o128; break;    // gin_w2[0]
        default: src = s5; Ksrc = 128; KP = 128; dstoff = 2 * o96 + 3 * o128; break;   // gin_w2[1]
    }
    int i = blockIdx.x * blockDim.x + threadIdx.x;
    if (i < 128 * KP) {
        int n = i / KP, k = i - n * KP;
        float v = (k < Ksrc) ? src[(size_t)k * DIMC + n] : 0.f;
        unsigned short hi = f2b(v);
        wlo[dstoff + i] = f2b(v - b2f(hi));
        whi[dstoff + i] = hi;
    }
}

// ---------------- BN coef + scaled w1 weights (fold BN affine into w1) ----------------

__launch_bounds__(256)
__global__ void k_bn_w(const float* __restrict__ bnsum, const float* __restrict__ gamma,
                       const float* __restrict__ beta, const float* __restrict__ w1,
                       float* __restrict__ coef, unsigned short* __restrict__ whiO,
                       unsigned short* __restrict__ wloO, float* __restrict__ cbeta, float invN) {
    __shared__ float sS[128], sT[128], sC[256];
    int t = threadIdx.x;
    if (t < 128) {
        float mu  = bnsum[t] * invN;
        float var = bnsum[128 + t] * invN - mu * mu;
        float inv = rsqrtf(var + 1e-5f);
        float s = gamma[t] * inv;
        float sh = beta[t] - mu * s;
        coef[t] = s; coef[128 + t] = sh;
        sS[t] = s; sT[t] = sh;
    }
    __syncthreads();
    for (int i = t; i < 16384; i += 256) {
        int n = i >> 7, k = i & 127;
        float v = w1[(size_t)k * 128 + n] * sS[k];
        unsigned short hi = f2b(v);
        whiO[i] = hi;
        wloO[i] = f2b(v - b2f(hi));
    }
    int n = t & 127, half = t >> 7;
    float acc = 0.f;
    for (int k = half * 64; k < half * 64 + 64; ++k) acc = fmaf(sT[k], w1[(size_t)k * 128 + n], acc);
    sC[t] = acc;
    __syncthreads();
    if (t < 128) cbeta[t] = sC[t] + sC[t + 128];
}

__global__ void k_bn_coef(const float* __restrict__ bnsum, const float* __restrict__ gamma,
                          const float* __restrict__ beta, float* __restrict__ coef, float invN) {
    int c = threadIdx.x;  // 128
    float mu  = bnsum[c] * invN;
    float var = bnsum[128 + c] * invN - mu * mu;
    float inv = rsqrtf(var + 1e-5f);
    float s = gamma[c] * inv;
    coef[c] = s;
    coef[128 + c] = beta[c] - mu * s;
}

// ---------------- MFMA GEMM (hi/lo planes in, hi/lo planes out) ----------------
// acc += Ahi*Whi + Ahi*Wlo + Alo*Whi. 128x128 tile, 4 waves of 64x64, K chunk 32.

template<int KP>
__launch_bounds__(256)
__global__ void k_gemm_hl(const unsigned short* __restrict__ Ahi,
                          const unsigned short* __restrict__ Alo,
                          const unsigned short* __restrict__ Whi,
                          const unsigned short* __restrict__ Wlo,
                          const float* __restrict__ bias,
                          const float* __restrict__ rowScale,
                          float* __restrict__ statsOut,
                          unsigned short* __restrict__ Chi,
                          unsigned short* __restrict__ Clo,
                          int N, int doRelu) {
    __shared__ unsigned short sAhi[4096], sAlo[4096], sBhi[4096], sBlo[4096];
    __shared__ float sStats[256];
    const int tid = threadIdx.x;
    const int row0 = blockIdx.x * 128;

    const int wave = tid >> 6;
    const int lane = tid & 63;
    const int lm = lane & 15, q = lane >> 4;
    const int wr = (wave >> 1) * 64, wc = (wave & 1) * 64;

    f32x4 acc[4][4];
#pragma unroll
    for (int a = 0; a < 4; ++a)
#pragma unroll
        for (int b = 0; b < 4; ++b) acc[a][b] = (f32x4){0.f, 0.f, 0.f, 0.f};

    for (int k0 = 0; k0 < KP; k0 += 32) {
        if (k0) __syncthreads();
        for (int s = tid; s < 512; s += 256) {
            int g = s & 3, r = s >> 2;
            int gr = row0 + r;
            size_t la = ((size_t)g * 128 + r) * 8;
            uint4 vh = make_uint4(0, 0, 0, 0), vl = make_uint4(0, 0, 0, 0);
            if (gr < N) {
                size_t ga = (size_t)gr * KP + k0 + g * 8;
                vh = *(const uint4*)(Ahi + ga);
                vl = *(const uint4*)(Alo + ga);
            }
            *(uint4*)(sAhi + la) = vh;
            *(uint4*)(sAlo + la) = vl;
            size_t gb = (size_t)r * KP + k0 + g * 8;
            *(uint4*)(sBhi + la) = *(const uint4*)(Whi + gb);
            *(uint4*)(sBlo + la) = *(const uint4*)(Wlo + gb);
        }
        __syncthreads();

        short8x ah[4], al[4], bh[4], bl[4];
#pragma unroll
        for (int rt = 0; rt < 4; ++rt) {
            size_t addr = ((size_t)q * 128 + wr + rt * 16 + lm) * 8;
            ah[rt] = *(const short8x*)(sAhi + addr);
            al[rt] = *(const short8x*)(sAlo + addr);
        }
#pragma unroll
        for (int ct = 0; ct < 4; ++ct) {
            size_t addr = ((size_t)q * 128 + wc + ct * 16 + lm) * 8;
            bh[ct] = *(const short8x*)(sBhi + addr);
            bl[ct] = *(const short8x*)(sBlo + addr);
        }
#pragma unroll
        for (int rt = 0; rt < 4; ++rt)
#pragma unroll
            for (int ct = 0; ct < 4; ++ct) {
                acc[rt][ct] = __builtin_amdgcn_mfma_f32_16x16x32_bf16(ah[rt], bh[ct], acc[rt][ct], 0, 0, 0);
                acc[rt][ct] = __builtin_amdgcn_mfma_f32_16x16x32_bf16(ah[rt], bl[ct], acc[rt][ct], 0, 0, 0);
                acc[rt][ct] = __builtin_amdgcn_mfma_f32_16x16x32_bf16(al[rt], bh[ct], acc[rt][ct], 0, 0, 0);
            }
    }

    float cs[4] = {0.f, 0.f, 0.f, 0.f}, cq[4] = {0.f, 0.f, 0.f, 0.f};
#pragma unroll
    for (int rt = 0; rt < 4; ++rt) {
#pragma unroll
        for (int i = 0; i < 4; ++i) {
            int row = wr + rt * 16 + q * 4 + i;
            int gr = row0 + row;
            if (gr < N) {
                float sc = rowScale ? rowScale[gr] : 1.f;
#pragma unroll
                for (int ct = 0; ct < 4; ++ct) {
                    int colg = wc + ct * 16 + lm;
                    float v = acc[rt][ct][i];
                    if (bias) v += bias[colg];
                    if (doRelu) v = fmaxf(v, 0.f);
                    v *= sc;
                    unsigned short hi = f2b(v);
                    Chi[(size_t)gr * DIMC + colg] = hi;
                    Clo[(size_t)gr * DIMC + colg] = f2b(v - b2f(hi));
                    if (statsOut) { cs[ct] += v; cq[ct] = fmaf(v, v, cq[ct]); }
                }
            }
        }
    }
    if (statsOut) {
        sStats[tid] = 0.f;
        __syncthreads();
#pragma unroll
        for (int ct = 0; ct < 4; ++ct) {
            int colg = wc + ct * 16 + lm;
            atomicAdd(&sStats[colg], cs[ct]);
            atomicAdd(&sStats[128 + colg], cq[ct]);
        }
        __syncthreads();
        atomicAdd(&statsOut[tid], sStats[tid]);
    }
}

// ---------------- CSR gather (hi/lo planes, fp32 accumulate) ----------------

__global__ void k_gather_gcn_hl(const unsigned short* __restrict__ thi, const unsigned short* __restrict__ tlo,
                                const int* __restrict__ rowptr, const int* __restrict__ col,
                                const float* __restrict__ dis, const float* __restrict__ bias,
                                unsigned short* __restrict__ ohi, unsigned short* __restrict__ olo, int N) {
    int i = blockIdx.x * blockDim.x + threadIdx.x;
    int node = i >> 4, c8 = (i & 15) * 8;
    if (node >= N) return;
    int s = rowptr[node], e = rowptr[node + 1];
    float acc[8];
    hl2f8(*(const uint4*)(thi + (size_t)node * DIMC + c8),
          *(const uint4*)(tlo + (size_t)node * DIMC + c8), acc);
    for (int k = s; k < e; ++k) {
        float f[8];
        size_t a = (size_t)col[k] * DIMC + c8;
        hl2f8(*(const uint4*)(thi + a), *(const uint4*)(tlo + a), f);
#pragma unroll
        for (int j = 0; j < 8; ++j) acc[j] += f[j];
    }
    float d = dis[node];
    float o[8];
#pragma unroll
    for (int j = 0; j < 8; ++j) o[j] = fmaxf(acc[j] * d + bias[c8 + j], 0.f);
    uint4 h, l;
    f82hl(o, h, l);
    *(uint4*)(ohi + (size_t)node * DIMC + c8) = h;
    *(uint4*)(olo + (size_t)node * DIMC + c8) = l;
}

__global__ void k_gather_gin_hl(const unsigned short* __restrict__ thi, const unsigned short* __restrict__ tlo,
                                const int* __restrict__ rowptr, const int* __restrict__ col,
                                const float* __restrict__ bias, const float* __restrict__ cbeta,
                                unsigned short* __restrict__ ohi, unsigned short* __restrict__ olo, int N) {
    int i = blockIdx.x * blockDim.x + threadIdx.x;
    int node = i >> 4, c8 = (i & 15) * 8;
    if (node >= N) return;
    int s = rowptr[node], e = rowptr[node + 1];
    float acc[8];
    hl2f8(*(const uint4*)(thi + (size_t)node * DIMC + c8),
          *(const uint4*)(tlo + (size_t)node * DIMC + c8), acc);
    for (int k = s; k < e; ++k) {
        float f[8];
        size_t a = (size_t)col[k] * DIMC + c8;
        hl2f8(*(const uint4*)(thi + a), *(const uint4*)(tlo + a), f);
#pragma unroll
        for (int j = 0; j < 8; ++j) acc[j] += f[j];
    }
    float deg1 = (float)(e - s + 1);
    float o[8];
#pragma unroll
    for (int j = 0; j < 8; ++j) {
        float v = acc[j] + bias[c8 + j];
        if (cbeta) v = fmaf(deg1, cbeta[c8 + j], v);
        o[j] = fmaxf(v, 0.f);
    }
    uint4 h, l;
    f82hl(o, h, l);
    *(uint4*)(ohi + (size_t)node * DIMC + c8) = h;
    *(uint4*)(olo + (size_t)node * DIMC + c8) = l;
}

// ---------------- segment max ----------------

__global__ void k_segmax_gin_all(const unsigned short* __restrict__ h0h, const unsigned short* __restrict__ h0l,
                                 const unsigned short* __restrict__ h1h, const unsigned short* __restrict__ h1l,
                                 const unsigned short* __restrict__ h2h, const unsigned short* __restrict__ h2l,
                                 const float* __restrict__ coef, const int* __restrict__ start,
                                 float* __restrict__ out) {
    int g = blockIdx.x, c = threadIdx.x;
    float s0 = coef[c],       t0 = coef[128 + c];
    float s1 = coef[256 + c], t1 = coef[384 + c];
    float s2 = coef[512 + c], t2 = coef[640 + c];
    int s = start[g], e = start[g + 1];
    float m0 = -INFINITY, m1 = -INFINITY, m2 = -INFINITY, mm = -INFINITY, me = -INFINITY;
    for (int n = s; n < e; ++n) {
        size_t idx = (size_t)n * DIMC + c;
        float a0 = fmaf(b2f(h0h[idx]) + b2f(h0l[idx]), s0, t0);
        float a1 = fmaf(b2f(h1h[idx]) + b2f(h1l[idx]), s1, t1);
        float a2 = fmaf(b2f(h2h[idx]) + b2f(h2l[idx]), s2, t2);
        m0 = fmaxf(m0, a0); m1 = fmaxf(m1, a1); m2 = fmaxf(m2, a2);
        mm = fmaxf(mm, a0 * a1 * a2);
        me = fmaxf(me, a0 + a1 + a2);
    }
    size_t o = (size_t)g * REPW + c;
    out[o]            = m0;
    out[o + 1 * DIMC] = m1;
    out[o + 2 * DIMC] = m2;
    out[o + 3 * DIMC] = mm;
    out[o + 4 * DIMC] = me;
}

__global__ void k_segmax_gcn(const unsigned short* __restrict__ g1h, const unsigned short* __restrict__ g1l,
                             const unsigned short* __restrict__ g2h, const unsigned short* __restrict__ g2l,
                             const int* __restrict__ start, float* __restrict__ out) {
    int g = blockIdx.x, c = threadIdx.x;
    int s = start[g], e = start[g + 1];
    float m1 = -INFINITY, m2 = -INFINITY, ma = -INFINITY, mm = -INFINITY;
    for (int n = s; n < e; ++n) {
        size_t idx = (size_t)n * DIMC + c;
        float a = b2f(g1h[idx]) + b2f(g1l[idx]);
        float b = b2f(g2h[idx]) + b2f(g2l[idx]);
        m1 = fmaxf(m1, a); m2 = fmaxf(m2, b);
        ma = fmaxf(ma, a + b); mm = fmaxf(mm, a * b);
    }
    size_t o = (size_t)g * REPW + c;
    out[o + 5 * DIMC] = m1;
    out[o + 6 * DIMC] = m2;
    out[o + 7 * DIMC] = ma;
    out[o + 8 * DIMC] = mm;
}

// ---------------- launch ----------------

extern "C" void kernel_launch(void* const* d_in, const int* in_sizes, int n_in,
                              void* d_out, int out_size, void* d_ws, size_t ws_size,
                              hipStream_t stream) {
    const float* x       = (const float*)d_in[0];
    const int*   ei      = (const int*)d_in[1];
    const int*   batch   = (const int*)d_in[2];
    const float* gcn1_W  = (const float*)d_in[4];
    const float* gcn1_b  = (const float*)d_in[5];
    const float* gcn2_W  = (const float*)d_in[6];
    const float* gcn2_b  = (const float*)d_in[7];
    const float* gin0_w1 = (const float*)d_in[8];
    const float* gin0_b1 = (const float*)d_in[9];
    const float* gin0_w2 = (const float*)d_in[10];
    const float* gin0_b2 = (const float*)d_in[11];
    const float* gin_w1  = (const float*)d_in[12];
    const float* gin_b1  = (const float*)d_in[13];
    const float* gin_w2  = (const float*)d_in[14];
    const float* gin_b2  = (const float*)d_in[15];
    const float* bn_g    = (const float*)d_in[16];
    const float* bn_b    = (const float*)d_in[17];
    float* out = (float*)d_out;

    const int N = in_sizes[0] / FINC;   // 100000
    const int E = in_sizes[1] / 2;      // 400000
    const int G = out_size / REPW;      // 2500
    const int* srcv = ei;
    const int* dstv = ei + E;

    auto cdiv = [](long a, long b) { return (int)((a + b - 1) / b); };
    const int gemmGrid = cdiv(N, 128);

    char* ws = (char*)d_ws;
    size_t off = 0;
    auto alloc = [&](size_t bytes) { char* p = ws + off; off += (bytes + 255) & ~(size_t)255; return p; };
    int*   cnt     = (int*)alloc(N * 4);
    int*   rowptr  = (int*)alloc((N + 1) * 4);
    int*   cursor  = (int*)alloc(N * 4);
    int*   col     = (int*)alloc(E * 4);
    float* dis     = (float*)alloc(N * 4);
    float* bnsum   = (float*)alloc(768 * 4);
    float* coef    = (float*)alloc(768 * 4);
    float* cbeta   = (float*)alloc(128 * 4);
    int*   start   = (int*)alloc((G + 1) * 4);
    int*   tileSum = (int*)alloc(256 * 4);
    int*   tileOff = (int*)alloc(256 * 4);
    const size_t wtElems = 2 * (size_t)128 * 96 + 4 * (size_t)128 * 128;
    unsigned short* whi = (unsigned short*)alloc(wtElems * 2);
    unsigned short* wlo = (unsigned short*)alloc(wtElems * 2);
    unsigned short* w1shi = (unsigned short*)alloc((size_t)128 * 128 * 2);
    unsigned short* w1slo = (unsigned short*)alloc((size_t)128 * 128 * 2);
    const size_t P = (size_t)N * DIMC;
    unsigned short* tThi = (unsigned short*)alloc(P * 2);
    unsigned short* tTlo = (unsigned short*)alloc(P * 2);
    unsigned short* zhi  = (unsigned short*)alloc(P * 2);
    unsigned short* zlo  = (unsigned short*)alloc(P * 2);
    unsigned short* h0hi = (unsigned short*)alloc(P * 2);
    unsigned short* h0lo = (unsigned short*)alloc(P * 2);
    unsigned short* h1hi = (unsigned short*)alloc(P * 2);
    unsigned short* h1lo = (unsigned short*)alloc(P * 2);
    unsigned short* h2hi = (unsigned short*)alloc(P * 2);
    unsigned short* h2lo = (unsigned short*)alloc(P * 2);
    // x planes (N x 96) aliased onto h2 planes: x dead after GIN0's first GEMM,
    // h2 first written in GIN layer 2's final GEMM.
    unsigned short* xhi = h2hi;
    unsigned short* xlo = h2lo;
    (void)ws_size; (void)n_in;

    const size_t o96 = (size_t)128 * 96, o128 = (size_t)128 * 128;
    // whi/wlo slots: 0 gcn1(96), 1 gin0_w1(96), 2 gcn2, 3 gin0_w2, 4 gin_w2[0], 5 gin_w2[1]
    const size_t woff[6] = {0, o96, 2 * o96, 2 * o96 + o128, 2 * o96 + 2 * o128, 2 * o96 + 3 * o128};

    const int T = 256;
    const int gatherGrid = cdiv((long)N * 16, T);
    const int nTiles = cdiv(N, SCAN_TILE);
    const float invN = 1.0f / (float)N;

    // ---- CSR build + norms + graph bounds + conversions ----
    k_fill_int<<<cdiv(N, T), T, 0, stream>>>(cnt, 0, N);
    k_count<<<cdiv(E, T), T, 0, stream>>>(dstv, cnt, E);
    k_tilesum<<<nTiles, T, 0, stream>>>(cnt, tileSum, N);
    k_tilescan<<<1, T, 0, stream>>>(tileSum, tileOff, rowptr, nTiles, N);
    k_tileemit<<<nTiles, T, 0, stream>>>(cnt, tileOff, rowptr, cursor, dis, N);
    k_scatter<<<cdiv(E, T), T, 0, stream>>>(srcv, dstv, cursor, col, E);
    k_bounds<<<cdiv(G + 1, T), T, 0, stream>>>(batch, start, N, G);
    k_fill<<<3, T, 0, stream>>>(bnsum, 0.f, 768);
    k_cvt_x<<<cdiv((long)N * 96, T), T, 0, stream>>>(x, xhi, xlo, N);
    {
        dim3 g(64, 6);
        k_cvt_w<<<g, T, 0, stream>>>(gcn1_W, gin0_w1, gcn2_W, gin0_w2,
                                     gin_w2, gin_w2 + o128, whi, wlo);
    }

    // ---- GCN branch (g1 in h1 planes, g2 in z planes) ----
    k_gemm_hl<96><<<gemmGrid, T, 0, stream>>>(xhi, xlo, whi + woff[0], wlo + woff[0],
                                              nullptr, dis, nullptr, tThi, tTlo, N, 0);
    k_gather_gcn_hl<<<gatherGrid, T, 0, stream>>>(tThi, tTlo, rowptr, col, dis, gcn1_b,
                                                  h1hi, h1lo, N);                        // g1
    k_gemm_hl<128><<<gemmGrid, T, 0, stream>>>(h1hi, h1lo, whi + woff[2], wlo + woff[2],
                                               nullptr, dis, nullptr, tThi, tTlo, N, 0);
    k_gather_gcn_hl<<<gatherGrid, T, 0, stream>>>(tThi, tTlo, rowptr, col, dis, gcn2_b,
                                                  zhi, zlo, N);                          // g2
    k_segmax_gcn<<<G, DIMC, 0, stream>>>(h1hi, h1lo, zhi, zlo, start, out);              // groups 5..8

    // ---- GIN layer 0 ----
    k_gemm_hl<96><<<gemmGrid, T, 0, stream>>>(xhi, xlo, whi + woff[1], wlo + woff[1],
                                              nullptr, nullptr, nullptr, tThi, tTlo, N, 0);
    k_gather_gin_hl<<<gatherGrid, T, 0, stream>>>(tThi, tTlo, rowptr, col, gin0_b1, nullptr,
                                                  zhi, zlo, N);
    k_gemm_hl<128><<<gemmGrid, T, 0, stream>>>(zhi, zlo, whi + woff[3], wlo + woff[3],
                                               gin0_b2, nullptr, bnsum, h0hi, h0lo, N, 1);

    // ---- GIN layers 1, 2 (BN folded into scaled w1 + degree-bias) ----
    const unsigned short* hsrc_hi[2] = {h0hi, h1hi};
    const unsigned short* hsrc_lo[2] = {h0lo, h1lo};
    unsigned short* hdst_hi[2] = {h1hi, h2hi};
    unsigned short* hdst_lo[2] = {h1lo, h2lo};
    for (int L = 1; L <= 2; ++L) {
        k_bn_w<<<1, T, 0, stream>>>(bnsum + (L - 1) * 256, bn_g + (L - 1) * DIMC, bn_b + (L - 1) * DIMC,
                                    gin_w1 + (size_t)(L - 1) * o128, coef + (L - 1) * 256,
                                    w1shi, w1slo, cbeta, invN);
        k_gemm_hl<128><<<gemmGrid, T, 0, stream>>>(hsrc_hi[L - 1], hsrc_lo[L - 1], w1shi, w1slo,
                                                   nullptr, nullptr, nullptr, tThi, tTlo, N, 0);
        k_gather_gin_hl<<<gatherGrid, T, 0, stream>>>(tThi, tTlo, rowptr, col,
                                                      gin_b1 + (size_t)(L - 1) * DIMC, cbeta,
                                                      zhi, zlo, N);
        k_gemm_hl<128><<<gemmGrid, T, 0, stream>>>(zhi, zlo, whi + woff[3 + L], wlo + woff[3 + L],
                                                   gin_b2 + (size_t)(L - 1) * DIMC, nullptr,
                                                   bnsum + L * 256, hdst_hi[L - 1], hdst_lo[L - 1], N, 1);
    }
    k_bn_coef<<<1, DIMC, 0, stream>>>(bnsum + 512, bn_g + 2 * DIMC, bn_b + 2 * DIMC, coef + 512, invN);

    k_segmax_gin_all<<<G, DIMC, 0, stream>>>(h0hi, h0lo, h1hi, h1lo, h2hi, h2lo,
                                             coef, start, out);                          // groups 0..4
}

// Round 9
// 846.555 us; speedup vs baseline: 1.0644x; 1.0644x over previous
//
#include <hip/hip_runtime.h>
#include <math.h>

#define DIMC 128
#define FINC 78
#define REPW 1152        // 9 * 128
#define SCAN_TILE 1024   // elements per scan tile (256 threads x 4)

typedef __attribute__((ext_vector_type(8))) short short8x;
typedef __attribute__((ext_vector_type(4))) float f32x4;

__device__ inline float b2f(unsigned short u) {
    union { unsigned int i; float f; } v; v.i = ((unsigned int)u) << 16; return v.f;
}
__device__ inline unsigned short f2b(float f) {
    union { float f; unsigned int i; } v; v.f = f;
    unsigned int r = (v.i + 0x7FFFu + ((v.i >> 16) & 1u)) >> 16;
    return (unsigned short)r;
}
// packed format: uint32 = (bf16_hi << 16) | bf16_lo ; value = hi + lo (~fp32)
__device__ inline float pf2f(unsigned int u) {
    union { unsigned int i; float f; } hi, lo;
    hi.i = u & 0xFFFF0000u;
    lo.i = u << 16;
    return hi.f + lo.f;
}
__device__ inline unsigned int f2pf(float v) {
    unsigned short hi = f2b(v);
    unsigned short lo = f2b(v - b2f(hi));
    return ((unsigned int)hi << 16) | (unsigned int)lo;
}
// accumulate 4 packed values into fp32 acc
__device__ inline void pfacc4(uint4 u, float* a) {
    a[0] += pf2f(u.x); a[1] += pf2f(u.y); a[2] += pf2f(u.z); a[3] += pf2f(u.w);
}

// ---------------- setup kernels ----------------

__global__ void k_fill_int(int* __restrict__ p, int v, int n) {
    int i = blockIdx.x * blockDim.x + threadIdx.x;
    if (i < n) p[i] = v;
}

__global__ void k_fill(float* __restrict__ p, float v, int n) {
    int i = blockIdx.x * blockDim.x + threadIdx.x;
    if (i < n) p[i] = v;
}

__global__ void k_count(const int* __restrict__ dst, int* __restrict__ cnt, int E) {
    int e = blockIdx.x * blockDim.x + threadIdx.x;
    if (e < E) atomicAdd(&cnt[dst[e]], 1);
}

__launch_bounds__(256)
__global__ void k_tilesum(const int* __restrict__ cnt, int* __restrict__ tileSum, int N) {
    __shared__ int red[256];
    int base = blockIdx.x * SCAN_TILE;
    int s = 0;
    for (int i = threadIdx.x; i < SCAN_TILE; i += 256) {
        int idx = base + i;
        if (idx < N) s += cnt[idx];
    }
    red[threadIdx.x] = s;
    __syncthreads();
    for (int d = 128; d > 0; d >>= 1) {
        if (threadIdx.x < d) red[threadIdx.x] += red[threadIdx.x + d];
        __syncthreads();
    }
    if (threadIdx.x == 0) tileSum[blockIdx.x] = red[0];
}

__launch_bounds__(256)
__global__ void k_tilescan(const int* __restrict__ tileSum, int* __restrict__ tileOff,
                           int* __restrict__ rowptr, int T, int N) {
    __shared__ int sh[256];
    int t = threadIdx.x;
    int orig = (t < T) ? tileSum[t] : 0;
    sh[t] = orig;
    __syncthreads();
    for (int d = 1; d < 256; d <<= 1) {
        int v = (t >= d) ? sh[t - d] : 0;
        __syncthreads();
        sh[t] += v;
        __syncthreads();
    }
    if (t < T) tileOff[t] = sh[t] - orig;
    if (t == 255) rowptr[N] = sh[255];
}

__launch_bounds__(256)
__global__ void k_tileemit(const int* __restrict__ cnt, const int* __restrict__ tileOff,
                           int* __restrict__ rowptr, int* __restrict__ cursor,
                           float* __restrict__ dis, int N) {
    __shared__ int sh[256];
    int t = threadIdx.x;
    int base = blockIdx.x * SCAN_TILE;
    int idx0 = base + t * 4;
    int v0 = 0, v1 = 0, v2 = 0, v3 = 0;
    if (idx0 + 3 < N) {
        int4 v = *(const int4*)(cnt + idx0);
        v0 = v.x; v1 = v.y; v2 = v.z; v3 = v.w;
    } else {
        if (idx0 + 0 < N) v0 = cnt[idx0 + 0];
        if (idx0 + 1 < N) v1 = cnt[idx0 + 1];
        if (idx0 + 2 < N) v2 = cnt[idx0 + 2];
        if (idx0 + 3 < N) v3 = cnt[idx0 + 3];
    }
    int s0 = v0, s1 = s0 + v1, s2 = s1 + v2, s3 = s2 + v3;
    sh[t] = s3;
    __syncthreads();
    for (int d = 1; d < 256; d <<= 1) {
        int v = (t >= d) ? sh[t - d] : 0;
        __syncthreads();
        sh[t] += v;
        __syncthreads();
    }
    int gbase = tileOff[blockIdx.x] + ((t == 0) ? 0 : sh[t - 1]);
    int ex[4] = {0, s0, s1, s2};
    int vv[4] = {v0, v1, v2, v3};
#pragma unroll
    for (int j = 0; j < 4; ++j) {
        int idx = idx0 + j;
        if (idx < N) {
            int r = gbase + ex[j];
            rowptr[idx] = r;
            cursor[idx] = r;
            dis[idx] = rsqrtf((float)vv[j] + 1.0f);
        }
    }
}

__global__ void k_scatter(const int* __restrict__ src, const int* __restrict__ dst,
                          int* __restrict__ cursor, int* __restrict__ col, int E) {
    int e = blockIdx.x * blockDim.x + threadIdx.x;
    if (e < E) {
        int pos = atomicAdd(&cursor[dst[e]], 1);
        col[pos] = src[e];
    }
}

__global__ void k_bounds(const int* __restrict__ batch, int* __restrict__ start, int N, int G) {
    int g = blockIdx.x * blockDim.x + threadIdx.x;
    if (g <= G) {
        int lo = 0, hi = N;
        while (lo < hi) { int mid = (lo + hi) >> 1; if (batch[mid] < g) lo = mid + 1; else hi = mid; }
        start[g] = lo;
    }
}

// ---------------- conversions ----------------

// x [N x 78] fp32 -> packed [N x 96] (zero-padded)
__global__ void k_cvt_x(const float* __restrict__ x, unsigned int* __restrict__ xpk, int N) {
    int i = blockIdx.x * blockDim.x + threadIdx.x;
    if (i < N * 96) {
        int n = i / 96, k = i - n * 96;
        float v = (k < FINC) ? x[(size_t)n * FINC + k] : 0.f;
        xpk[i] = f2pf(v);
    }
}

// weights -> transposed bf16 hi/lo planes [n][k]
__global__ void k_cvt_w(const float* __restrict__ s0, const float* __restrict__ s1,
                        const float* __restrict__ s2, const float* __restrict__ s3,
                        const float* __restrict__ s4, const float* __restrict__ s5,
                        unsigned short* __restrict__ whi, unsigned short* __restrict__ wlo) {
    int my = blockIdx.y;
    const float* src; int Ksrc, KP; size_t dstoff;
    const size_t o96 = (size_t)128 * 96, o128 = (size_t)128 * 128;
    switch (my) {
        case 0: src = s0; Ksrc = 78;  KP = 96;  dstoff = 0; break;             // gcn1
        case 1: src = s1; Ksrc = 78;  KP = 96;  dstoff = o96; break;           // gin0_w1
        case 2: src = s2; Ksrc = 128; KP = 128; dstoff = 2 * o96; break;       // gcn2
        case 3: src = s3; Ksrc = 128; KP = 128; dstoff = 2 * o96 + o128; break;        // gin0_w2
        case 4: src = s4; Ksrc = 128; KP = 128; dstoff = 2 * o96 + 2 * o128; break;    // gin_w2[0]
        default: src = s5; Ksrc = 128; KP = 128; dstoff = 2 * o96 + 3 * o128; break;   // gin_w2[1]
    }
    int i = blockIdx.x * blockDim.x + threadIdx.x;
    if (i < 128 * KP) {
        int n = i / KP, k = i - n * KP;
        float v = (k < Ksrc) ? src[(size_t)k * DIMC + n] : 0.f;
        unsigned short hi = f2b(v);
        wlo[dstoff + i] = f2b(v - b2f(hi));
        whi[dstoff + i] = hi;
    }
}

// ---------------- BN coef + scaled w1 weights (fold BN affine into w1) ----------------

__launch_bounds__(256)
__global__ void k_bn_w(const float* __restrict__ bnsum, const float* __restrict__ gamma,
                       const float* __restrict__ beta, const float* __restrict__ w1,
                       float* __restrict__ coef, unsigned short* __restrict__ whiO,
                       unsigned short* __restrict__ wloO, float* __restrict__ cbeta, float invN) {
    __shared__ float sS[128], sT[128], sC[256];
    int t = threadIdx.x;
    if (t < 128) {
        float mu  = bnsum[t] * invN;
        float var = bnsum[128 + t] * invN - mu * mu;
        float inv = rsqrtf(var + 1e-5f);
        float s = gamma[t] * inv;
        float sh = beta[t] - mu * s;
        coef[t] = s; coef[128 + t] = sh;
        sS[t] = s; sT[t] = sh;
    }
    __syncthreads();
    for (int i = t; i < 16384; i += 256) {
        int n = i >> 7, k = i & 127;
        float v = w1[(size_t)k * 128 + n] * sS[k];
        unsigned short hi = f2b(v);
        whiO[i] = hi;
        wloO[i] = f2b(v - b2f(hi));
    }
    int n = t & 127, half = t >> 7;
    float acc = 0.f;
    for (int k = half * 64; k < half * 64 + 64; ++k) acc = fmaf(sT[k], w1[(size_t)k * 128 + n], acc);
    sC[t] = acc;
    __syncthreads();
    if (t < 128) cbeta[t] = sC[t] + sC[t + 128];
}

__global__ void k_bn_coef(const float* __restrict__ bnsum, const float* __restrict__ gamma,
                          const float* __restrict__ beta, float* __restrict__ coef, float invN) {
    int c = threadIdx.x;  // 128
    float mu  = bnsum[c] * invN;
    float var = bnsum[128 + c] * invN - mu * mu;
    float inv = rsqrtf(var + 1e-5f);
    float s = gamma[c] * inv;
    coef[c] = s;
    coef[128 + c] = beta[c] - mu * s;
}

// ---------------- MFMA GEMM (packed A in, packed C out) ----------------
// A packed uint32 [N x KP]; W = Whi/Wlo bf16 planes transposed [128 x KP].
// acc += Ahi*Whi + Ahi*Wlo + Alo*Whi. 128x128 tile, 4 waves of 64x64, K chunk 32.

template<int KP>
__launch_bounds__(256)
__global__ void k_gemm_pf(const unsigned int* __restrict__ Apk,
                          const unsigned short* __restrict__ Whi,
                          const unsigned short* __restrict__ Wlo,
                          const float* __restrict__ bias,
                          const float* __restrict__ rowScale,
                          float* __restrict__ statsOut,
                          unsigned int* __restrict__ Cpk,
                          int N, int doRelu) {
    __shared__ unsigned short sAhi[4096], sAlo[4096], sBhi[4096], sBlo[4096];
    __shared__ float sStats[256];
    const int tid = threadIdx.x;
    const int row0 = blockIdx.x * 128;

    const int wave = tid >> 6;
    const int lane = tid & 63;
    const int lm = lane & 15, q = lane >> 4;
    const int wr = (wave >> 1) * 64, wc = (wave & 1) * 64;

    f32x4 acc[4][4];
#pragma unroll
    for (int a = 0; a < 4; ++a)
#pragma unroll
        for (int b = 0; b < 4; ++b) acc[a][b] = (f32x4){0.f, 0.f, 0.f, 0.f};

    for (int k0 = 0; k0 < KP; k0 += 32) {
        if (k0) __syncthreads();
        for (int s = tid; s < 512; s += 256) {
            int g = s & 3, r = s >> 2;
            int gr = row0 + r;
            size_t la = ((size_t)g * 128 + r) * 8;
            uint4 h = make_uint4(0, 0, 0, 0), l = make_uint4(0, 0, 0, 0);
            if (gr < N) {
                const unsigned int* p = Apk + (size_t)gr * KP + k0 + g * 8;
                uint4 u0 = *(const uint4*)(p);
                uint4 u1 = *(const uint4*)(p + 4);
                h.x = (u0.x >> 16) | (u0.y & 0xFFFF0000u);
                l.x = (u0.x & 0xFFFFu) | (u0.y << 16);
                h.y = (u0.z >> 16) | (u0.w & 0xFFFF0000u);
                l.y = (u0.z & 0xFFFFu) | (u0.w << 16);
                h.z = (u1.x >> 16) | (u1.y & 0xFFFF0000u);
                l.z = (u1.x & 0xFFFFu) | (u1.y << 16);
                h.w = (u1.z >> 16) | (u1.w & 0xFFFF0000u);
                l.w = (u1.z & 0xFFFFu) | (u1.w << 16);
            }
            *(uint4*)(sAhi + la) = h;
            *(uint4*)(sAlo + la) = l;
            size_t gb = (size_t)r * KP + k0 + g * 8;
            *(uint4*)(sBhi + la) = *(const uint4*)(Whi + gb);
            *(uint4*)(sBlo + la) = *(const uint4*)(Wlo + gb);
        }
        __syncthreads();

        short8x ah[4], al[4], bh[4], bl[4];
#pragma unroll
        for (int rt = 0; rt < 4; ++rt) {
            size_t addr = ((size_t)q * 128 + wr + rt * 16 + lm) * 8;
            ah[rt] = *(const short8x*)(sAhi + addr);
            al[rt] = *(const short8x*)(sAlo + addr);
        }
#pragma unroll
        for (int ct = 0; ct < 4; ++ct) {
            size_t addr = ((size_t)q * 128 + wc + ct * 16 + lm) * 8;
            bh[ct] = *(const short8x*)(sBhi + addr);
            bl[ct] = *(const short8x*)(sBlo + addr);
        }
#pragma unroll
        for (int rt = 0; rt < 4; ++rt)
#pragma unroll
            for (int ct = 0; ct < 4; ++ct) {
                acc[rt][ct] = __builtin_amdgcn_mfma_f32_16x16x32_bf16(ah[rt], bh[ct], acc[rt][ct], 0, 0, 0);
                acc[rt][ct] = __builtin_amdgcn_mfma_f32_16x16x32_bf16(ah[rt], bl[ct], acc[rt][ct], 0, 0, 0);
                acc[rt][ct] = __builtin_amdgcn_mfma_f32_16x16x32_bf16(al[rt], bh[ct], acc[rt][ct], 0, 0, 0);
            }
    }

    float cs[4] = {0.f, 0.f, 0.f, 0.f}, cq[4] = {0.f, 0.f, 0.f, 0.f};
#pragma unroll
    for (int rt = 0; rt < 4; ++rt) {
#pragma unroll
        for (int i = 0; i < 4; ++i) {
            int row = wr + rt * 16 + q * 4 + i;
            int gr = row0 + row;
            if (gr < N) {
                float sc = rowScale ? rowScale[gr] : 1.f;
#pragma unroll
                for (int ct = 0; ct < 4; ++ct) {
                    int colg = wc + ct * 16 + lm;
                    float v = acc[rt][ct][i];
                    if (bias) v += bias[colg];
                    if (doRelu) v = fmaxf(v, 0.f);
                    v *= sc;
                    Cpk[(size_t)gr * DIMC + colg] = f2pf(v);
                    if (statsOut) { cs[ct] += v; cq[ct] = fmaf(v, v, cq[ct]); }
                }
            }
        }
    }
    if (statsOut) {
        sStats[tid] = 0.f;
        __syncthreads();
#pragma unroll
        for (int ct = 0; ct < 4; ++ct) {
            int colg = wc + ct * 16 + lm;
            atomicAdd(&sStats[colg], cs[ct]);
            atomicAdd(&sStats[128 + colg], cq[ct]);
        }
        __syncthreads();
        atomicAdd(&statsOut[tid], sStats[tid]);
    }
}

// ---------------- CSR gather (packed, fp32 accumulate) ----------------
// 32 lanes per node, 4 packed elements (16 B) per lane; single gather stream.

__global__ void k_gather_gcn_pf(const unsigned int* __restrict__ t, const int* __restrict__ rowptr,
                                const int* __restrict__ col, const float* __restrict__ dis,
                                const float* __restrict__ bias, unsigned int* __restrict__ out, int N) {
    int i = blockIdx.x * blockDim.x + threadIdx.x;
    int node = i >> 5, c4 = (i & 31) * 4;
    if (node >= N) return;
    int s = rowptr[node], e = rowptr[node + 1];
    float acc[4] = {0.f, 0.f, 0.f, 0.f};
    pfacc4(*(const uint4*)(t + (size_t)node * DIMC + c4), acc);
    int k = s;
    for (; k + 1 < e; k += 2) {
        uint4 v0 = *(const uint4*)(t + (size_t)col[k] * DIMC + c4);
        uint4 v1 = *(const uint4*)(t + (size_t)col[k + 1] * DIMC + c4);
        pfacc4(v0, acc);
        pfacc4(v1, acc);
    }
    if (k < e) pfacc4(*(const uint4*)(t + (size_t)col[k] * DIMC + c4), acc);
    float d = dis[node];
    uint4 r;
    r.x = f2pf(fmaxf(acc[0] * d + bias[c4 + 0], 0.f));
    r.y = f2pf(fmaxf(acc[1] * d + bias[c4 + 1], 0.f));
    r.z = f2pf(fmaxf(acc[2] * d + bias[c4 + 2], 0.f));
    r.w = f2pf(fmaxf(acc[3] * d + bias[c4 + 3], 0.f));
    *(uint4*)(out + (size_t)node * DIMC + c4) = r;
}

__global__ void k_gather_gin_pf(const unsigned int* __restrict__ t, const int* __restrict__ rowptr,
                                const int* __restrict__ col, const float* __restrict__ bias,
                                const float* __restrict__ cbeta, unsigned int* __restrict__ out, int N) {
    int i = blockIdx.x * blockDim.x + threadIdx.x;
    int node = i >> 5, c4 = (i & 31) * 4;
    if (node >= N) return;
    int s = rowptr[node], e = rowptr[node + 1];
    float acc[4] = {0.f, 0.f, 0.f, 0.f};
    pfacc4(*(const uint4*)(t + (size_t)node * DIMC + c4), acc);
    int k = s;
    for (; k + 1 < e; k += 2) {
        uint4 v0 = *(const uint4*)(t + (size_t)col[k] * DIMC + c4);
        uint4 v1 = *(const uint4*)(t + (size_t)col[k + 1] * DIMC + c4);
        pfacc4(v0, acc);
        pfacc4(v1, acc);
    }
    if (k < e) pfacc4(*(const uint4*)(t + (size_t)col[k] * DIMC + c4), acc);
    float deg1 = (float)(e - s + 1);
    uint4 r;
#pragma unroll
    for (int j = 0; j < 4; ++j) {
        float v = acc[j] + bias[c4 + j];
        if (cbeta) v = fmaf(deg1, cbeta[c4 + j], v);
        ((unsigned int*)&r)[j] = f2pf(fmaxf(v, 0.f));
    }
    *(uint4*)(out + (size_t)node * DIMC + c4) = r;
}

// ---------------- segment max (packed inputs, fp32 output) ----------------

__global__ void k_segmax_gin_all(const unsigned int* __restrict__ h0, const unsigned int* __restrict__ h1,
                                 const unsigned int* __restrict__ h2, const float* __restrict__ coef,
                                 const int* __restrict__ start, float* __restrict__ out) {
    int g = blockIdx.x, c = threadIdx.x;
    float s0 = coef[c],       t0 = coef[128 + c];
    float s1 = coef[256 + c], t1 = coef[384 + c];
    float s2 = coef[512 + c], t2 = coef[640 + c];
    int s = start[g], e = start[g + 1];
    float m0 = -INFINITY, m1 = -INFINITY, m2 = -INFINITY, mm = -INFINITY, me = -INFINITY;
    for (int n = s; n < e; ++n) {
        size_t idx = (size_t)n * DIMC + c;
        float a0 = fmaf(pf2f(h0[idx]), s0, t0);
        float a1 = fmaf(pf2f(h1[idx]), s1, t1);
        float a2 = fmaf(pf2f(h2[idx]), s2, t2);
        m0 = fmaxf(m0, a0); m1 = fmaxf(m1, a1); m2 = fmaxf(m2, a2);
        mm = fmaxf(mm, a0 * a1 * a2);
        me = fmaxf(me, a0 + a1 + a2);
    }
    size_t o = (size_t)g * REPW + c;
    out[o]            = m0;
    out[o + 1 * DIMC] = m1;
    out[o + 2 * DIMC] = m2;
    out[o + 3 * DIMC] = mm;
    out[o + 4 * DIMC] = me;
}

__global__ void k_segmax_gcn(const unsigned int* __restrict__ G1, const unsigned int* __restrict__ G2,
                             const int* __restrict__ start, float* __restrict__ out) {
    int g = blockIdx.x, c = threadIdx.x;
    int s = start[g], e = start[g + 1];
    float m1 = -INFINITY, m2 = -INFINITY, ma = -INFINITY, mm = -INFINITY;
    for (int n = s; n < e; ++n) {
        size_t idx = (size_t)n * DIMC + c;
        float a = pf2f(G1[idx]);
        float b = pf2f(G2[idx]);
        m1 = fmaxf(m1, a); m2 = fmaxf(m2, b);
        ma = fmaxf(ma, a + b); mm = fmaxf(mm, a * b);
    }
    size_t o = (size_t)g * REPW + c;
    out[o + 5 * DIMC] = m1;
    out[o + 6 * DIMC] = m2;
    out[o + 7 * DIMC] = ma;
    out[o + 8 * DIMC] = mm;
}

// ---------------- launch ----------------

extern "C" void kernel_launch(void* const* d_in, const int* in_sizes, int n_in,
                              void* d_out, int out_size, void* d_ws, size_t ws_size,
                              hipStream_t stream) {
    const float* x       = (const float*)d_in[0];
    const int*   ei      = (const int*)d_in[1];
    const int*   batch   = (const int*)d_in[2];
    const float* gcn1_W  = (const float*)d_in[4];
    const float* gcn1_b  = (const float*)d_in[5];
    const float* gcn2_W  = (const float*)d_in[6];
    const float* gcn2_b  = (const float*)d_in[7];
    const float* gin0_w1 = (const float*)d_in[8];
    const float* gin0_b1 = (const float*)d_in[9];
    const float* gin0_w2 = (const float*)d_in[10];
    const float* gin0_b2 = (const float*)d_in[11];
    const float* gin_w1  = (const float*)d_in[12];
    const float* gin_b1  = (const float*)d_in[13];
    const float* gin_w2  = (const float*)d_in[14];
    const float* gin_b2  = (const float*)d_in[15];
    const float* bn_g    = (const float*)d_in[16];
    const float* bn_b    = (const float*)d_in[17];
    float* out = (float*)d_out;

    const int N = in_sizes[0] / FINC;   // 100000
    const int E = in_sizes[1] / 2;      // 400000
    const int G = out_size / REPW;      // 2500
    const int* srcv = ei;
    const int* dstv = ei + E;

    auto cdiv = [](long a, long b) { return (int)((a + b - 1) / b); };
    const int gemmGrid = cdiv(N, 128);

    char* ws = (char*)d_ws;
    size_t off = 0;
    auto alloc = [&](size_t bytes) { char* p = ws + off; off += (bytes + 255) & ~(size_t)255; return p; };
    int*   cnt     = (int*)alloc(N * 4);
    int*   rowptr  = (int*)alloc((N + 1) * 4);
    int*   cursor  = (int*)alloc(N * 4);
    int*   col     = (int*)alloc(E * 4);
    float* dis     = (float*)alloc(N * 4);
    float* bnsum   = (float*)alloc(768 * 4);
    float* coef    = (float*)alloc(768 * 4);
    float* cbeta   = (float*)alloc(128 * 4);
    int*   start   = (int*)alloc((G + 1) * 4);
    int*   tileSum = (int*)alloc(256 * 4);
    int*   tileOff = (int*)alloc(256 * 4);
    const size_t wtElems = 2 * (size_t)128 * 96 + 4 * (size_t)128 * 128;
    unsigned short* whi = (unsigned short*)alloc(wtElems * 2);
    unsigned short* wlo = (unsigned short*)alloc(wtElems * 2);
    unsigned short* w1shi = (unsigned short*)alloc((size_t)128 * 128 * 2);
    unsigned short* w1slo = (unsigned short*)alloc((size_t)128 * 128 * 2);
    const size_t P = (size_t)N * DIMC;
    unsigned int* tT = (unsigned int*)alloc(P * 4);
    unsigned int* z  = (unsigned int*)alloc(P * 4);
    unsigned int* h0 = (unsigned int*)alloc(P * 4);
    unsigned int* h1 = (unsigned int*)alloc(P * 4);
    unsigned int* h2 = (unsigned int*)alloc(P * 4);
    // x packed (N x 96) aliased onto h2: x dead after GIN0's first GEMM,
    // h2 first written in GIN layer 2's final GEMM.
    unsigned int* xpk = h2;
    (void)ws_size; (void)n_in;

    const size_t o96 = (size_t)128 * 96, o128 = (size_t)128 * 128;
    // whi/wlo slots: 0 gcn1(96), 1 gin0_w1(96), 2 gcn2, 3 gin0_w2, 4 gin_w2[0], 5 gin_w2[1]
    const size_t woff[6] = {0, o96, 2 * o96, 2 * o96 + o128, 2 * o96 + 2 * o128, 2 * o96 + 3 * o128};

    const int T = 256;
    const int gatherGrid = cdiv((long)N * 32, T);
    const int nTiles = cdiv(N, SCAN_TILE);
    const float invN = 1.0f / (float)N;

    // ---- CSR build + norms + graph bounds + conversions ----
    k_fill_int<<<cdiv(N, T), T, 0, stream>>>(cnt, 0, N);
    k_count<<<cdiv(E, T), T, 0, stream>>>(dstv, cnt, E);
    k_tilesum<<<nTiles, T, 0, stream>>>(cnt, tileSum, N);
    k_tilescan<<<1, T, 0, stream>>>(tileSum, tileOff, rowptr, nTiles, N);
    k_tileemit<<<nTiles, T, 0, stream>>>(cnt, tileOff, rowptr, cursor, dis, N);
    k_scatter<<<cdiv(E, T), T, 0, stream>>>(srcv, dstv, cursor, col, E);
    k_bounds<<<cdiv(G + 1, T), T, 0, stream>>>(batch, start, N, G);
    k_fill<<<3, T, 0, stream>>>(bnsum, 0.f, 768);
    k_cvt_x<<<cdiv((long)N * 96, T), T, 0, stream>>>(x, xpk, N);
    {
        dim3 g(64, 6);
        k_cvt_w<<<g, T, 0, stream>>>(gcn1_W, gin0_w1, gcn2_W, gin0_w2,
                                     gin_w2, gin_w2 + o128, whi, wlo);
    }

    // ---- GCN branch (g1 in h1, g2 in z) ----
    k_gemm_pf<96><<<gemmGrid, T, 0, stream>>>(xpk, whi + woff[0], wlo + woff[0],
                                              nullptr, dis, nullptr, tT, N, 0);
    k_gather_gcn_pf<<<gatherGrid, T, 0, stream>>>(tT, rowptr, col, dis, gcn1_b, h1, N);   // g1
    k_gemm_pf<128><<<gemmGrid, T, 0, stream>>>(h1, whi + woff[2], wlo + woff[2],
                                               nullptr, dis, nullptr, tT, N, 0);
    k_gather_gcn_pf<<<gatherGrid, T, 0, stream>>>(tT, rowptr, col, dis, gcn2_b, z, N);    // g2
    k_segmax_gcn<<<G, DIMC, 0, stream>>>(h1, z, start, out);                              // groups 5..8

    // ---- GIN layer 0 ----
    k_gemm_pf<96><<<gemmGrid, T, 0, stream>>>(xpk, whi + woff[1], wlo + woff[1],
                                              nullptr, nullptr, nullptr, tT, N, 0);
    k_gather_gin_pf<<<gatherGrid, T, 0, stream>>>(tT, rowptr, col, gin0_b1, nullptr, z, N);
    k_gemm_pf<128><<<gemmGrid, T, 0, stream>>>(z, whi + woff[3], wlo + woff[3],
                                               gin0_b2, nullptr, bnsum, h0, N, 1);

    // ---- GIN layers 1, 2 (BN folded into scaled w1 + degree-bias) ----
    const unsigned int* hsrc[2] = {h0, h1};
    unsigned int* hdst[2] = {h1, h2};
    for (int L = 1; L <= 2; ++L) {
        k_bn_w<<<1, T, 0, stream>>>(bnsum + (L - 1) * 256, bn_g + (L - 1) * DIMC, bn_b + (L - 1) * DIMC,
                                    gin_w1 + (size_t)(L - 1) * o128, coef + (L - 1) * 256,
                                    w1shi, w1slo, cbeta, invN);
        k_gemm_pf<128><<<gemmGrid, T, 0, stream>>>(hsrc[L - 1], w1shi, w1slo,
                                                   nullptr, nullptr, nullptr, tT, N, 0);
        k_gather_gin_pf<<<gatherGrid, T, 0, stream>>>(tT, rowptr, col,
                                                      gin_b1 + (size_t)(L - 1) * DIMC, cbeta, z, N);
        k_gemm_pf<128><<<gemmGrid, T, 0, stream>>>(z, whi + woff[3 + L], wlo + woff[3 + L],
                                                   gin_b2 + (size_t)(L - 1) * DIMC, nullptr,
                                                   bnsum + L * 256, hdst[L - 1], N, 1);
    }
    k_bn_coef<<<1, DIMC, 0, stream>>>(bnsum + 512, bn_g + 2 * DIMC, bn_b + 2 * DIMC, coef + 512, invN);

    k_segmax_gin_all<<<G, DIMC, 0, stream>>>(h0, h1, h2, coef, start, out);               // groups 0..4
}

// Round 10
// 812.021 us; speedup vs baseline: 1.1096x; 1.0425x over previous
//
#include <hip/hip_runtime.h>
#include <math.h>

#define DIMC 128
#define FINC 78
#define REPW 1152        // 9 * 128
#define SCAN_TILE 1024   // elements per scan tile (256 threads x 4)

typedef __attribute__((ext_vector_type(8))) short short8x;
typedef __attribute__((ext_vector_type(4))) float f32x4;

__device__ inline float b2f(unsigned short u) {
    union { unsigned int i; float f; } v; v.i = ((unsigned int)u) << 16; return v.f;
}
__device__ inline unsigned short f2b(float f) {
    union { float f; unsigned int i; } v; v.f = f;
    unsigned int r = (v.i + 0x7FFFu + ((v.i >> 16) & 1u)) >> 16;
    return (unsigned short)r;
}
// packed format: uint32 = (bf16_hi << 16) | bf16_lo ; value = hi + lo (~fp32)
__device__ inline float pf2f(unsigned int u) {
    union { unsigned int i; float f; } hi, lo;
    hi.i = u & 0xFFFF0000u;
    lo.i = u << 16;
    return hi.f + lo.f;
}
__device__ inline unsigned int f2pf(float v) {
    unsigned short hi = f2b(v);
    unsigned short lo = f2b(v - b2f(hi));
    return ((unsigned int)hi << 16) | (unsigned int)lo;
}
__device__ inline void pfacc4(uint4 u, float* a) {
    a[0] += pf2f(u.x); a[1] += pf2f(u.y); a[2] += pf2f(u.z); a[3] += pf2f(u.w);
}

// ---------------- setup kernels ----------------

__global__ void k_fill_int(int* __restrict__ p, int v, int n) {
    int i = blockIdx.x * blockDim.x + threadIdx.x;
    if (i < n) p[i] = v;
}

__global__ void k_fill(float* __restrict__ p, float v, int n) {
    int i = blockIdx.x * blockDim.x + threadIdx.x;
    if (i < n) p[i] = v;
}

__global__ void k_count(const int* __restrict__ dst, int* __restrict__ cnt, int E) {
    int e = blockIdx.x * blockDim.x + threadIdx.x;
    if (e < E) atomicAdd(&cnt[dst[e]], 1);
}

__launch_bounds__(256)
__global__ void k_tilesum(const int* __restrict__ cnt, int* __restrict__ tileSum, int N) {
    __shared__ int red[256];
    int base = blockIdx.x * SCAN_TILE;
    int s = 0;
    for (int i = threadIdx.x; i < SCAN_TILE; i += 256) {
        int idx = base + i;
        if (idx < N) s += cnt[idx];
    }
    red[threadIdx.x] = s;
    __syncthreads();
    for (int d = 128; d > 0; d >>= 1) {
        if (threadIdx.x < d) red[threadIdx.x] += red[threadIdx.x + d];
        __syncthreads();
    }
    if (threadIdx.x == 0) tileSum[blockIdx.x] = red[0];
}

__launch_bounds__(256)
__global__ void k_tilescan(const int* __restrict__ tileSum, int* __restrict__ tileOff,
                           int* __restrict__ rowptr, int T, int N) {
    __shared__ int sh[256];
    int t = threadIdx.x;
    int orig = (t < T) ? tileSum[t] : 0;
    sh[t] = orig;
    __syncthreads();
    for (int d = 1; d < 256; d <<= 1) {
        int v = (t >= d) ? sh[t - d] : 0;
        __syncthreads();
        sh[t] += v;
        __syncthreads();
    }
    if (t < T) tileOff[t] = sh[t] - orig;
    if (t == 255) rowptr[N] = sh[255];
}

__launch_bounds__(256)
__global__ void k_tileemit(const int* __restrict__ cnt, const int* __restrict__ tileOff,
                           int* __restrict__ rowptr, int* __restrict__ cursor,
                           float* __restrict__ dis, int N) {
    __shared__ int sh[256];
    int t = threadIdx.x;
    int base = blockIdx.x * SCAN_TILE;
    int idx0 = base + t * 4;
    int v0 = 0, v1 = 0, v2 = 0, v3 = 0;
    if (idx0 + 3 < N) {
        int4 v = *(const int4*)(cnt + idx0);
        v0 = v.x; v1 = v.y; v2 = v.z; v3 = v.w;
    } else {
        if (idx0 + 0 < N) v0 = cnt[idx0 + 0];
        if (idx0 + 1 < N) v1 = cnt[idx0 + 1];
        if (idx0 + 2 < N) v2 = cnt[idx0 + 2];
        if (idx0 + 3 < N) v3 = cnt[idx0 + 3];
    }
    int s0 = v0, s1 = s0 + v1, s2 = s1 + v2, s3 = s2 + v3;
    sh[t] = s3;
    __syncthreads();
    for (int d = 1; d < 256; d <<= 1) {
        int v = (t >= d) ? sh[t - d] : 0;
        __syncthreads();
        sh[t] += v;
        __syncthreads();
    }
    int gbase = tileOff[blockIdx.x] + ((t == 0) ? 0 : sh[t - 1]);
    int ex[4] = {0, s0, s1, s2};
    int vv[4] = {v0, v1, v2, v3};
#pragma unroll
    for (int j = 0; j < 4; ++j) {
        int idx = idx0 + j;
        if (idx < N) {
            int r = gbase + ex[j];
            rowptr[idx] = r;
            cursor[idx] = r;
            dis[idx] = rsqrtf((float)vv[j] + 1.0f);
        }
    }
}

__global__ void k_scatter(const int* __restrict__ src, const int* __restrict__ dst,
                          int* __restrict__ cursor, int* __restrict__ col, int E) {
    int e = blockIdx.x * blockDim.x + threadIdx.x;
    if (e < E) {
        int pos = atomicAdd(&cursor[dst[e]], 1);
        col[pos] = src[e];
    }
}

__global__ void k_bounds(const int* __restrict__ batch, int* __restrict__ start, int N, int G) {
    int g = blockIdx.x * blockDim.x + threadIdx.x;
    if (g <= G) {
        int lo = 0, hi = N;
        while (lo < hi) { int mid = (lo + hi) >> 1; if (batch[mid] < g) lo = mid + 1; else hi = mid; }
        start[g] = lo;
    }
}

// ---------------- conversions ----------------

__global__ void k_cvt_x(const float* __restrict__ x, unsigned int* __restrict__ xpk, int N) {
    int i = blockIdx.x * blockDim.x + threadIdx.x;
    if (i < N * 96) {
        int n = i / 96, k = i - n * 96;
        float v = (k < FINC) ? x[(size_t)n * FINC + k] : 0.f;
        xpk[i] = f2pf(v);
    }
}

__global__ void k_cvt_w(const float* __restrict__ s0, const float* __restrict__ s1,
                        const float* __restrict__ s2, const float* __restrict__ s3,
                        const float* __restrict__ s4, const float* __restrict__ s5,
                        unsigned short* __restrict__ whi, unsigned short* __restrict__ wlo) {
    int my = blockIdx.y;
    const float* src; int Ksrc, KP; size_t dstoff;
    const size_t o96 = (size_t)128 * 96, o128 = (size_t)128 * 128;
    switch (my) {
        case 0: src = s0; Ksrc = 78;  KP = 96;  dstoff = 0; break;             // gcn1
        case 1: src = s1; Ksrc = 78;  KP = 96;  dstoff = o96; break;           // gin0_w1
        case 2: src = s2; Ksrc = 128; KP = 128; dstoff = 2 * o96; break;       // gcn2
        case 3: src = s3; Ksrc = 128; KP = 128; dstoff = 2 * o96 + o128; break;        // gin0_w2
        case 4: src = s4; Ksrc = 128; KP = 128; dstoff = 2 * o96 + 2 * o128; break;    // gin_w2[0]
        default: src = s5; Ksrc = 128; KP = 128; dstoff = 2 * o96 + 3 * o128; break;   // gin_w2[1]
    }
    int i = blockIdx.x * blockDim.x + threadIdx.x;
    if (i < 128 * KP) {
        int n = i / KP, k = i - n * KP;
        float v = (k < Ksrc) ? src[(size_t)k * DIMC + n] : 0.f;
        unsigned short hi = f2b(v);
        wlo[dstoff + i] = f2b(v - b2f(hi));
        whi[dstoff + i] = hi;
    }
}

// ---------------- BN coef + scaled w1 weights ----------------

__launch_bounds__(256)
__global__ void k_bn_w(const float* __restrict__ bnsum, const float* __restrict__ gamma,
                       const float* __restrict__ beta, const float* __restrict__ w1,
                       float* __restrict__ coef, unsigned short* __restrict__ whiO,
                       unsigned short* __restrict__ wloO, float* __restrict__ cbeta, float invN) {
    __shared__ float sS[128], sT[128], sC[256];
    int t = threadIdx.x;
    if (t < 128) {
        float mu  = bnsum[t] * invN;
        float var = bnsum[128 + t] * invN - mu * mu;
        float inv = rsqrtf(var + 1e-5f);
        float s = gamma[t] * inv;
        float sh = beta[t] - mu * s;
        coef[t] = s; coef[128 + t] = sh;
        sS[t] = s; sT[t] = sh;
    }
    __syncthreads();
    for (int i = t; i < 16384; i += 256) {
        int n = i >> 7, k = i & 127;
        float v = w1[(size_t)k * 128 + n] * sS[k];
        unsigned short hi = f2b(v);
        whiO[i] = hi;
        wloO[i] = f2b(v - b2f(hi));
    }
    int n = t & 127, half = t >> 7;
    float acc = 0.f;
    for (int k = half * 64; k < half * 64 + 64; ++k) acc = fmaf(sT[k], w1[(size_t)k * 128 + n], acc);
    sC[t] = acc;
    __syncthreads();
    if (t < 128) cbeta[t] = sC[t] + sC[t + 128];
}

__global__ void k_bn_coef(const float* __restrict__ bnsum, const float* __restrict__ gamma,
                          const float* __restrict__ beta, float* __restrict__ coef, float invN) {
    int c = threadIdx.x;  // 128
    float mu  = bnsum[c] * invN;
    float var = bnsum[128 + c] * invN - mu * mu;
    float inv = rsqrtf(var + 1e-5f);
    float s = gamma[c] * inv;
    coef[c] = s;
    coef[128 + c] = beta[c] - mu * s;
}

// ---------------- MFMA GEMM (packed A, packed C), 64-row tiles ----------------
// 64x128 tile per block, 4 waves each computing 64x32. Grid = cdiv(N,64) for
// ~6 blocks/CU residency (LDS ~25 KB). LDS group-stride padded (66 / 130
// units of 16 B) to kill staging-write bank conflicts.

template<int KP>
__launch_bounds__(256)
__global__ void k_gemm_pf(const unsigned int* __restrict__ Apk,
                          const unsigned short* __restrict__ Whi,
                          const unsigned short* __restrict__ Wlo,
                          const float* __restrict__ bias,
                          const float* __restrict__ rowScale,
                          float* __restrict__ statsOut,
                          unsigned int* __restrict__ Cpk,
                          int N, int doRelu) {
    __shared__ unsigned short sAhi[4 * 66 * 8], sAlo[4 * 66 * 8];
    __shared__ unsigned short sBhi[4 * 130 * 8], sBlo[4 * 130 * 8];
    __shared__ float sStats[256];
    const int tid = threadIdx.x;
    const int row0 = blockIdx.x * 64;

    const int wave = tid >> 6;
    const int lane = tid & 63;
    const int lm = lane & 15, q = lane >> 4;
    const int wc = wave * 32;

    f32x4 acc[4][2];
#pragma unroll
    for (int a = 0; a < 4; ++a)
#pragma unroll
        for (int b = 0; b < 2; ++b) acc[a][b] = (f32x4){0.f, 0.f, 0.f, 0.f};

    for (int k0 = 0; k0 < KP; k0 += 32) {
        if (k0) __syncthreads();
        // stage A: 64 rows x 4 groups of 8 packed, one slot per thread
        {
            int g = tid & 3, r = tid >> 2;   // r in [0,64)
            int gr = row0 + r;
            uint4 h = make_uint4(0, 0, 0, 0), l = make_uint4(0, 0, 0, 0);
            if (gr < N) {
                const unsigned int* p = Apk + (size_t)gr * KP + k0 + g * 8;
                uint4 u0 = *(const uint4*)(p);
                uint4 u1 = *(const uint4*)(p + 4);
                h.x = (u0.x >> 16) | (u0.y & 0xFFFF0000u);
                l.x = (u0.x & 0xFFFFu) | (u0.y << 16);
                h.y = (u0.z >> 16) | (u0.w & 0xFFFF0000u);
                l.y = (u0.z & 0xFFFFu) | (u0.w << 16);
                h.z = (u1.x >> 16) | (u1.y & 0xFFFF0000u);
                l.z = (u1.x & 0xFFFFu) | (u1.y << 16);
                h.w = (u1.z >> 16) | (u1.w & 0xFFFF0000u);
                l.w = (u1.z & 0xFFFFu) | (u1.w << 16);
            }
            size_t la = ((size_t)g * 66 + r) * 8;
            *(uint4*)(sAhi + la) = h;
            *(uint4*)(sAlo + la) = l;
        }
        // stage B: 128 cols x 4 groups, two slots per thread
        for (int s = tid; s < 512; s += 256) {
            int g = s & 3, n = s >> 2;
            size_t gb = (size_t)n * KP + k0 + g * 8;
            size_t la = ((size_t)g * 130 + n) * 8;
            *(uint4*)(sBhi + la) = *(const uint4*)(Whi + gb);
            *(uint4*)(sBlo + la) = *(const uint4*)(Wlo + gb);
        }
        __syncthreads();

        short8x ah[4], al[4], bh[2], bl[2];
#pragma unroll
        for (int rt = 0; rt < 4; ++rt) {
            size_t addr = ((size_t)q * 66 + rt * 16 + lm) * 8;
            ah[rt] = *(const short8x*)(sAhi + addr);
            al[rt] = *(const short8x*)(sAlo + addr);
        }
#pragma unroll
        for (int ct = 0; ct < 2; ++ct) {
            size_t addr = ((size_t)q * 130 + wc + ct * 16 + lm) * 8;
            bh[ct] = *(const short8x*)(sBhi + addr);
            bl[ct] = *(const short8x*)(sBlo + addr);
        }
#pragma unroll
        for (int rt = 0; rt < 4; ++rt)
#pragma unroll
            for (int ct = 0; ct < 2; ++ct) {
                acc[rt][ct] = __builtin_amdgcn_mfma_f32_16x16x32_bf16(ah[rt], bh[ct], acc[rt][ct], 0, 0, 0);
                acc[rt][ct] = __builtin_amdgcn_mfma_f32_16x16x32_bf16(ah[rt], bl[ct], acc[rt][ct], 0, 0, 0);
                acc[rt][ct] = __builtin_amdgcn_mfma_f32_16x16x32_bf16(al[rt], bh[ct], acc[rt][ct], 0, 0, 0);
            }
    }

    float cs[2] = {0.f, 0.f}, cq[2] = {0.f, 0.f};
#pragma unroll
    for (int rt = 0; rt < 4; ++rt) {
#pragma unroll
        for (int i = 0; i < 4; ++i) {
            int row = rt * 16 + q * 4 + i;
            int gr = row0 + row;
            if (gr < N) {
                float sc = rowScale ? rowScale[gr] : 1.f;
#pragma unroll
                for (int ct = 0; ct < 2; ++ct) {
                    int colg = wc + ct * 16 + lm;
                    float v = acc[rt][ct][i];
                    if (bias) v += bias[colg];
                    if (doRelu) v = fmaxf(v, 0.f);
                    v *= sc;
                    Cpk[(size_t)gr * DIMC + colg] = f2pf(v);
                    if (statsOut) { cs[ct] += v; cq[ct] = fmaf(v, v, cq[ct]); }
                }
            }
        }
    }
    if (statsOut) {
        sStats[tid] = 0.f;
        __syncthreads();
#pragma unroll
        for (int ct = 0; ct < 2; ++ct) {
            int colg = wc + ct * 16 + lm;
            atomicAdd(&sStats[colg], cs[ct]);
            atomicAdd(&sStats[128 + colg], cq[ct]);
        }
        __syncthreads();
        atomicAdd(&statsOut[tid], sStats[tid]);
    }
}

// ---------------- CSR gather (packed, fp32 accumulate) ----------------

__global__ void k_gather_gcn_pf(const unsigned int* __restrict__ t, const int* __restrict__ rowptr,
                                const int* __restrict__ col, const float* __restrict__ dis,
                                const float* __restrict__ bias, unsigned int* __restrict__ out, int N) {
    int i = blockIdx.x * blockDim.x + threadIdx.x;
    int node = i >> 5, c4 = (i & 31) * 4;
    if (node >= N) return;
    int s = rowptr[node], e = rowptr[node + 1];
    float acc[4] = {0.f, 0.f, 0.f, 0.f};
    pfacc4(*(const uint4*)(t + (size_t)node * DIMC + c4), acc);
    int k = s;
    for (; k + 1 < e; k += 2) {
        uint4 v0 = *(const uint4*)(t + (size_t)col[k] * DIMC + c4);
        uint4 v1 = *(const uint4*)(t + (size_t)col[k + 1] * DIMC + c4);
        pfacc4(v0, acc);
        pfacc4(v1, acc);
    }
    if (k < e) pfacc4(*(const uint4*)(t + (size_t)col[k] * DIMC + c4), acc);
    float d = dis[node];
    uint4 r;
    r.x = f2pf(fmaxf(acc[0] * d + bias[c4 + 0], 0.f));
    r.y = f2pf(fmaxf(acc[1] * d + bias[c4 + 1], 0.f));
    r.z = f2pf(fmaxf(acc[2] * d + bias[c4 + 2], 0.f));
    r.w = f2pf(fmaxf(acc[3] * d + bias[c4 + 3], 0.f));
    *(uint4*)(out + (size_t)node * DIMC + c4) = r;
}

__global__ void k_gather_gin_pf(const unsigned int* __restrict__ t, const int* __restrict__ rowptr,
                                const int* __restrict__ col, const float* __restrict__ bias,
                                const float* __restrict__ cbeta, unsigned int* __restrict__ out, int N) {
    int i = blockIdx.x * blockDim.x + threadIdx.x;
    int node = i >> 5, c4 = (i & 31) * 4;
    if (node >= N) return;
    int s = rowptr[node], e = rowptr[node + 1];
    float acc[4] = {0.f, 0.f, 0.f, 0.f};
    pfacc4(*(const uint4*)(t + (size_t)node * DIMC + c4), acc);
    int k = s;
    for (; k + 1 < e; k += 2) {
        uint4 v0 = *(const uint4*)(t + (size_t)col[k] * DIMC + c4);
        uint4 v1 = *(const uint4*)(t + (size_t)col[k + 1] * DIMC + c4);
        pfacc4(v0, acc);
        pfacc4(v1, acc);
    }
    if (k < e) pfacc4(*(const uint4*)(t + (size_t)col[k] * DIMC + c4), acc);
    float deg1 = (float)(e - s + 1);
    uint4 r;
#pragma unroll
    for (int j = 0; j < 4; ++j) {
        float v = acc[j] + bias[c4 + j];
        if (cbeta) v = fmaf(deg1, cbeta[c4 + j], v);
        ((unsigned int*)&r)[j] = f2pf(fmaxf(v, 0.f));
    }
    *(uint4*)(out + (size_t)node * DIMC + c4) = r;
}

// ---------------- segment max (packed inputs, fp32 output) ----------------

__global__ void k_segmax_gin_all(const unsigned int* __restrict__ h0, const unsigned int* __restrict__ h1,
                                 const unsigned int* __restrict__ h2, const float* __restrict__ coef,
                                 const int* __restrict__ start, float* __restrict__ out) {
    int g = blockIdx.x, c = threadIdx.x;
    float s0 = coef[c],       t0 = coef[128 + c];
    float s1 = coef[256 + c], t1 = coef[384 + c];
    float s2 = coef[512 + c], t2 = coef[640 + c];
    int s = start[g], e = start[g + 1];
    float m0 = -INFINITY, m1 = -INFINITY, m2 = -INFINITY, mm = -INFINITY, me = -INFINITY;
    for (int n = s; n < e; ++n) {
        size_t idx = (size_t)n * DIMC + c;
        float a0 = fmaf(pf2f(h0[idx]), s0, t0);
        float a1 = fmaf(pf2f(h1[idx]), s1, t1);
        float a2 = fmaf(pf2f(h2[idx]), s2, t2);
        m0 = fmaxf(m0, a0); m1 = fmaxf(m1, a1); m2 = fmaxf(m2, a2);
        mm = fmaxf(mm, a0 * a1 * a2);
        me = fmaxf(me, a0 + a1 + a2);
    }
    size_t o = (size_t)g * REPW + c;
    out[o]            = m0;
    out[o + 1 * DIMC] = m1;
    out[o + 2 * DIMC] = m2;
    out[o + 3 * DIMC] = mm;
    out[o + 4 * DIMC] = me;
}

__global__ void k_segmax_gcn(const unsigned int* __restrict__ G1, const unsigned int* __restrict__ G2,
                             const int* __restrict__ start, float* __restrict__ out) {
    int g = blockIdx.x, c = threadIdx.x;
    int s = start[g], e = start[g + 1];
    float m1 = -INFINITY, m2 = -INFINITY, ma = -INFINITY, mm = -INFINITY;
    for (int n = s; n < e; ++n) {
        size_t idx = (size_t)n * DIMC + c;
        float a = pf2f(G1[idx]);
        float b = pf2f(G2[idx]);
        m1 = fmaxf(m1, a); m2 = fmaxf(m2, b);
        ma = fmaxf(ma, a + b); mm = fmaxf(mm, a * b);
    }
    size_t o = (size_t)g * REPW + c;
    out[o + 5 * DIMC] = m1;
    out[o + 6 * DIMC] = m2;
    out[o + 7 * DIMC] = ma;
    out[o + 8 * DIMC] = mm;
}

// ---------------- launch ----------------

extern "C" void kernel_launch(void* const* d_in, const int* in_sizes, int n_in,
                              void* d_out, int out_size, void* d_ws, size_t ws_size,
                              hipStream_t stream) {
    const float* x       = (const float*)d_in[0];
    const int*   ei      = (const int*)d_in[1];
    const int*   batch   = (const int*)d_in[2];
    const float* gcn1_W  = (const float*)d_in[4];
    const float* gcn1_b  = (const float*)d_in[5];
    const float* gcn2_W  = (const float*)d_in[6];
    const float* gcn2_b  = (const float*)d_in[7];
    const float* gin0_w1 = (const float*)d_in[8];
    const float* gin0_b1 = (const float*)d_in[9];
    const float* gin0_w2 = (const float*)d_in[10];
    const float* gin0_b2 = (const float*)d_in[11];
    const float* gin_w1  = (const float*)d_in[12];
    const float* gin_b1  = (const float*)d_in[13];
    const float* gin_w2  = (const float*)d_in[14];
    const float* gin_b2  = (const float*)d_in[15];
    const float* bn_g    = (const float*)d_in[16];
    const float* bn_b    = (const float*)d_in[17];
    float* out = (float*)d_out;

    const int N = in_sizes[0] / FINC;   // 100000
    const int E = in_sizes[1] / 2;      // 400000
    const int G = out_size / REPW;      // 2500
    const int* srcv = ei;
    const int* dstv = ei + E;

    auto cdiv = [](long a, long b) { return (int)((a + b - 1) / b); };
    const int gemmGrid = cdiv(N, 64);

    char* ws = (char*)d_ws;
    size_t off = 0;
    auto alloc = [&](size_t bytes) { char* p = ws + off; off += (bytes + 255) & ~(size_t)255; return p; };
    int*   cnt     = (int*)alloc(N * 4);
    int*   rowptr  = (int*)alloc((N + 1) * 4);
    int*   cursor  = (int*)alloc(N * 4);
    int*   col     = (int*)alloc(E * 4);
    float* dis     = (float*)alloc(N * 4);
    float* bnsum   = (float*)alloc(768 * 4);
    float* coef    = (float*)alloc(768 * 4);
    float* cbeta   = (float*)alloc(128 * 4);
    int*   start   = (int*)alloc((G + 1) * 4);
    int*   tileSum = (int*)alloc(256 * 4);
    int*   tileOff = (int*)alloc(256 * 4);
    const size_t wtElems = 2 * (size_t)128 * 96 + 4 * (size_t)128 * 128;
    unsigned short* whi = (unsigned short*)alloc(wtElems * 2);
    unsigned short* wlo = (unsigned short*)alloc(wtElems * 2);
    unsigned short* w1shi = (unsigned short*)alloc((size_t)128 * 128 * 2);
    unsigned short* w1slo = (unsigned short*)alloc((size_t)128 * 128 * 2);
    const size_t P = (size_t)N * DIMC;
    unsigned int* tT = (unsigned int*)alloc(P * 4);
    unsigned int* z  = (unsigned int*)alloc(P * 4);
    unsigned int* h0 = (unsigned int*)alloc(P * 4);
    unsigned int* h1 = (unsigned int*)alloc(P * 4);
    unsigned int* h2 = (unsigned int*)alloc(P * 4);
    // x packed (N x 96) aliased onto h2: x dead after GIN0's first GEMM,
    // h2 first written in GIN layer 2's final GEMM.
    unsigned int* xpk = h2;
    (void)ws_size; (void)n_in;

    const size_t o96 = (size_t)128 * 96, o128 = (size_t)128 * 128;
    const size_t woff[6] = {0, o96, 2 * o96, 2 * o96 + o128, 2 * o96 + 2 * o128, 2 * o96 + 3 * o128};

    const int T = 256;
    const int gatherGrid = cdiv((long)N * 32, T);
    const int nTiles = cdiv(N, SCAN_TILE);
    const float invN = 1.0f / (float)N;

    // ---- CSR build + norms + graph bounds + conversions ----
    k_fill_int<<<cdiv(N, T), T, 0, stream>>>(cnt, 0, N);
    k_count<<<cdiv(E, T), T, 0, stream>>>(dstv, cnt, E);
    k_tilesum<<<nTiles, T, 0, stream>>>(cnt, tileSum, N);
    k_tilescan<<<1, T, 0, stream>>>(tileSum, tileOff, rowptr, nTiles, N);
    k_tileemit<<<nTiles, T, 0, stream>>>(cnt, tileOff, rowptr, cursor, dis, N);
    k_scatter<<<cdiv(E, T), T, 0, stream>>>(srcv, dstv, cursor, col, E);
    k_bounds<<<cdiv(G + 1, T), T, 0, stream>>>(batch, start, N, G);
    k_fill<<<3, T, 0, stream>>>(bnsum, 0.f, 768);
    k_cvt_x<<<cdiv((long)N * 96, T), T, 0, stream>>>(x, xpk, N);
    {
        dim3 g(64, 6);
        k_cvt_w<<<g, T, 0, stream>>>(gcn1_W, gin0_w1, gcn2_W, gin0_w2,
                                     gin_w2, gin_w2 + o128, whi, wlo);
    }

    // ---- GCN branch (g1 in h1, g2 in z) ----
    k_gemm_pf<96><<<gemmGrid, T, 0, stream>>>(xpk, whi + woff[0], wlo + woff[0],
                                              nullptr, dis, nullptr, tT, N, 0);
    k_gather_gcn_pf<<<gatherGrid, T, 0, stream>>>(tT, rowptr, col, dis, gcn1_b, h1, N);   // g1
    k_gemm_pf<128><<<gemmGrid, T, 0, stream>>>(h1, whi + woff[2], wlo + woff[2],
                                               nullptr, dis, nullptr, tT, N, 0);
    k_gather_gcn_pf<<<gatherGrid, T, 0, stream>>>(tT, rowptr, col, dis, gcn2_b, z, N);    // g2
    k_segmax_gcn<<<G, DIMC, 0, stream>>>(h1, z, start, out);                              // groups 5..8

    // ---- GIN layer 0 ----
    k_gemm_pf<96><<<gemmGrid, T, 0, stream>>>(xpk, whi + woff[1], wlo + woff[1],
                                              nullptr, nullptr, nullptr, tT, N, 0);
    k_gather_gin_pf<<<gatherGrid, T, 0, stream>>>(tT, rowptr, col, gin0_b1, nullptr, z, N);
    k_gemm_pf<128><<<gemmGrid, T, 0, stream>>>(z, whi + woff[3], wlo + woff[3],
                                               gin0_b2, nullptr, bnsum, h0, N, 1);

    // ---- GIN layers 1, 2 (BN folded into scaled w1 + degree-bias) ----
    const unsigned int* hsrc[2] = {h0, h1};
    unsigned int* hdst[2] = {h1, h2};
    for (int L = 1; L <= 2; ++L) {
        k_bn_w<<<1, T, 0, stream>>>(bnsum + (L - 1) * 256, bn_g + (L - 1) * DIMC, bn_b + (L - 1) * DIMC,
                                    gin_w1 + (size_t)(L - 1) * o128, coef + (L - 1) * 256,
                                    w1shi, w1slo, cbeta, invN);
        k_gemm_pf<128><<<gemmGrid, T, 0, stream>>>(hsrc[L - 1], w1shi, w1slo,
                                                   nullptr, nullptr, nullptr, tT, N, 0);
        k_gather_gin_pf<<<gatherGrid, T, 0, stream>>>(tT, rowptr, col,
                                                      gin_b1 + (size_t)(L - 1) * DIMC, cbeta, z, N);
        k_gemm_pf<128><<<gemmGrid, T, 0, stream>>>(z, whi + woff[3 + L], wlo + woff[3 + L],
                                                   gin_b2 + (size_t)(L - 1) * DIMC, nullptr,
                                                   bnsum + L * 256, hdst[L - 1], N, 1);
    }
    k_bn_coef<<<1, DIMC, 0, stream>>>(bnsum + 512, bn_g + 2 * DIMC, bn_b + 2 * DIMC, coef + 512, invN);

    k_segmax_gin_all<<<G, DIMC, 0, stream>>>(h0, h1, h2, coef, start, out);               // groups 0..4
}